// Round 4
// baseline (104.810 us; speedup 1.0000x reference)
//
#include <hip/hip_runtime.h>
#include <math.h>

// QuantumLayer, restructured (round 4 = round 3 with the 0.5x epilogue bug
// fixed: the lane butterfly over masks {2,4,8} already counts each |phi_i|^2
// exactly once, so no 0.5 compensation).
//  The entangling layers (Rot+CNOT, shared across batch) form one fixed
//  256x256 unitary U. The embedding makes a REAL product state psi(b).
//  K1: gate-simulate the 256 basis columns (round-1-verified code, 1 column
//      per wave), store Bt[n=2i+c][j] = {Re,Im}U[i][j] bf16 (256 KB, d_ws).
//  K2: per 32 batch rows: fp32 projection+sigmoid -> psi tile (bf16, LDS)
//      -> MFMA GEMM (M=32,N=512,K=256) vs Bt -> |phi|^2 -> signed trees
//      -> 8 <Z_w> per row.
// Amp-index convention everywhere: wire w <-> bit (7-w) of amp index i.

namespace {

constexpr float PI_F = 3.14159265358979323846f;

typedef short     bf16x8  __attribute__((ext_vector_type(8)));
typedef float     f32x4   __attribute__((ext_vector_type(4)));
typedef unsigned short u16x8 __attribute__((ext_vector_type(8)));
typedef unsigned short u16x4 __attribute__((ext_vector_type(4)));

struct Cx { float re, im; };

__device__ __forceinline__ float shfx(float v, int m) {
  return __shfl_xor(v, m, 64);
}

__device__ __forceinline__ unsigned short f2bf(float f) {
  unsigned u = __builtin_bit_cast(unsigned, f);
  unsigned r = u + 0x7fff + ((u >> 16) & 1);   // round-to-nearest-even
  return (unsigned short)(r >> 16);
}

// ---------------- K1: round-1-verified 4-amps/lane gate simulator ----------

__device__ __forceinline__ void mix2(Cx &a, Cx &b,
    float u00r, float u00i, float u01r, float u01i,
    float u10r, float u10i, float u11r, float u11i) {
  float ar = a.re, ai = a.im, br = b.re, bi = b.im;
  a.re = u00r*ar - u00i*ai + u01r*br - u01i*bi;
  a.im = u00r*ai + u00i*ar + u01r*bi + u01i*br;
  b.re = u10r*ar - u10i*ai + u11r*br - u11i*bi;
  b.im = u10r*ai + u10i*ar + u11r*bi + u11i*br;
}

// i = lane*4 + k; wires 0..5 = lane bits 5..0, wires 6..7 = local bits 1..0.
template<int W>
__device__ __forceinline__ void apply1q(Cx s[4],
    float u00r, float u00i, float u01r, float u01i,
    float u10r, float u10i, float u11r, float u11i, int lane) {
  if constexpr (W == 7) {
    mix2(s[0], s[1], u00r,u00i,u01r,u01i,u10r,u10i,u11r,u11i);
    mix2(s[2], s[3], u00r,u00i,u01r,u01i,u10r,u10i,u11r,u11i);
  } else if constexpr (W == 6) {
    mix2(s[0], s[2], u00r,u00i,u01r,u01i,u10r,u10i,u11r,u11i);
    mix2(s[1], s[3], u00r,u00i,u01r,u01i,u10r,u10i,u11r,u11i);
  } else {
    constexpr int lm = 1 << (5 - W);
    const bool hi = (lane & lm) != 0;
    float cAr = hi ? u11r : u00r, cAi = hi ? u11i : u00i;
    float cBr = hi ? u10r : u01r, cBi = hi ? u10i : u01i;
#pragma unroll
    for (int k = 0; k < 4; ++k) {
      float tr = shfx(s[k].re, lm), ti = shfx(s[k].im, lm);
      float mr = s[k].re, mi = s[k].im;
      s[k].re = cAr*mr - cAi*mi + cBr*tr - cBi*ti;
      s[k].im = cAr*mi + cAi*mr + cBr*ti + cBi*tr;
    }
  }
}

// PennyLane Rot = RZ(om) RY(th) RZ(phi); qw[L][W][0..2] = phi,th,om.
template<int L, int W>
__device__ __forceinline__ void rotW(Cx s[4], const float* __restrict__ qw, int lane) {
  float phi = qw[L*24 + W*3 + 0];
  float th  = qw[L*24 + W*3 + 1];
  float om  = qw[L*24 + W*3 + 2];
  float c  = __cosf(0.5f*th), sn = __sinf(0.5f*th);
  float a  = 0.5f*(phi + om), d = 0.5f*(phi - om);
  float ca = __cosf(a), sa = __sinf(a);
  float cd = __cosf(d), sd = __sinf(d);
  apply1q<W>(s, c*ca, -c*sa, -sn*cd, -sn*sd, sn*cd, -sn*sd, c*ca, c*sa, lane);
}

__device__ __forceinline__ void swapc(Cx &a, Cx &b) { Cx t = a; a = b; b = t; }

__device__ __forceinline__ void cswap(Cx &a, Cx &b, bool c) {
  float ar = a.re, ai = a.im;
  a.re = c ? b.re : a.re;  a.im = c ? b.im : a.im;
  b.re = c ? ar : b.re;    b.im = c ? ai : b.im;
}

template<int CW, int TW>
__device__ __forceinline__ void cnot(Cx s[4], int lane) {
  constexpr int pc = 7 - CW, pt = 7 - TW;
  if constexpr (pc >= 2 && pt >= 2) {
    constexpr int lmC = 1 << (pc - 2), lmT = 1 << (pt - 2);
    const bool ctl = (lane & lmC) != 0;
#pragma unroll
    for (int k = 0; k < 4; ++k) {
      float tr = shfx(s[k].re, lmT), ti = shfx(s[k].im, lmT);
      s[k].re = ctl ? tr : s[k].re;
      s[k].im = ctl ? ti : s[k].im;
    }
  } else if constexpr (pc >= 2 && pt < 2) {
    constexpr int lmC = 1 << (pc - 2);
    const bool ctl = (lane & lmC) != 0;
    if constexpr (pt == 0) { cswap(s[0], s[1], ctl); cswap(s[2], s[3], ctl); }
    else                   { cswap(s[0], s[2], ctl); cswap(s[1], s[3], ctl); }
  } else if constexpr (pc < 2 && pt >= 2) {
    constexpr int lmT = 1 << (pt - 2);
    constexpr int k0 = (pc == 0) ? 1 : 2;
    s[k0].re = shfx(s[k0].re, lmT); s[k0].im = shfx(s[k0].im, lmT);
    s[3].re  = shfx(s[3].re,  lmT); s[3].im  = shfx(s[3].im,  lmT);
  } else {
    if constexpr (pc == 1) swapc(s[2], s[3]);
    else                   swapc(s[1], s[3]);
  }
}

template<int L>
__device__ __forceinline__ void rotLayer(Cx s[4], const float* __restrict__ qw, int lane) {
  rotW<L,0>(s, qw, lane); rotW<L,1>(s, qw, lane);
  rotW<L,2>(s, qw, lane); rotW<L,3>(s, qw, lane);
  rotW<L,4>(s, qw, lane); rotW<L,5>(s, qw, lane);
  rotW<L,6>(s, qw, lane); rotW<L,7>(s, qw, lane);
}

// K1: build U columns, write Bt[n][k] bf16 (n=2i+c in 0..511, k=j in 0..255).
__global__ __launch_bounds__(256) void build_u_kernel(
    const float* __restrict__ qw, unsigned short* __restrict__ Bt) {
  __shared__ __align__(16) float ucol[4 * 512];
  const int tid  = threadIdx.x;
  const int lane = tid & 63;
  const int wv   = tid >> 6;
  const int j    = blockIdx.x * 4 + wv;      // basis column, 0..255

  Cx s[4];
#pragma unroll
  for (int k = 0; k < 4; ++k) { s[k].re = 0.f; s[k].im = 0.f; }
  const int jl = j >> 2, jk = j & 3;
#pragma unroll
  for (int k = 0; k < 4; ++k)
    s[k].re = (lane == jl && k == jk) ? 1.f : 0.f;

  rotLayer<0>(s, qw, lane);   // r=1
  cnot<0,1>(s, lane); cnot<1,2>(s, lane); cnot<2,3>(s, lane); cnot<3,4>(s, lane);
  cnot<4,5>(s, lane); cnot<5,6>(s, lane); cnot<6,7>(s, lane); cnot<7,0>(s, lane);
  rotLayer<1>(s, qw, lane);   // r=2
  cnot<0,2>(s, lane); cnot<1,3>(s, lane); cnot<2,4>(s, lane); cnot<3,5>(s, lane);
  cnot<4,6>(s, lane); cnot<5,7>(s, lane); cnot<6,0>(s, lane); cnot<7,1>(s, lane);
  rotLayer<2>(s, qw, lane);   // r=3
  cnot<0,3>(s, lane); cnot<1,4>(s, lane); cnot<2,5>(s, lane); cnot<3,6>(s, lane);
  cnot<4,7>(s, lane); cnot<5,0>(s, lane); cnot<6,1>(s, lane); cnot<7,2>(s, lane);

  // stage: ucol[wv*512 + 2i + c], i = lane*4+k -> 8 contiguous floats per lane
  float* dst = &ucol[wv*512 + lane*8];
  dst[0]=s[0].re; dst[1]=s[0].im; dst[2]=s[1].re; dst[3]=s[1].im;
  dst[4]=s[2].re; dst[5]=s[2].im; dst[6]=s[3].re; dst[7]=s[3].im;
  __syncthreads();

  // transpose-write: Bt[n][j0+jj] for this block's 4 columns
  const int j0 = blockIdx.x * 4;
#pragma unroll
  for (int rep = 0; rep < 2; ++rep) {
    int n = tid + rep * 256;
    u16x4 v;
#pragma unroll
    for (int jj = 0; jj < 4; ++jj) v[jj] = f2bf(ucol[jj*512 + n]);
    *(u16x4*)(Bt + (size_t)n * 256 + j0) = v;
  }
}

// ---------------- K2: psi build + MFMA GEMM + Z epilogue -------------------
// Block: 256 thr (4 waves), 32 batch rows, N=512 (interleaved re/im), K=256.

__global__ __launch_bounds__(256) void qgemm_kernel(
    const float* __restrict__ x, const float* __restrict__ Wm,
    const float* __restrict__ bvec, const float* __restrict__ scale,
    const float* __restrict__ bias, const unsigned short* __restrict__ Bt,
    float* __restrict__ out) {
  constexpr int APITCH = 264;                 // 256 + 8 bf16 pad (bank spread)
  __shared__ __align__(16) unsigned short Ash[32 * APITCH];
  __shared__ __align__(16) float tTab[32][16];
  __shared__ __align__(16) float zpart[4][32][8];

  const int tid  = threadIdx.x;
  const int lane = tid & 63;
  const int wv   = tid >> 6;
  const int b0   = blockIdx.x * 32;

  // ---- Phase A: proj + sigmoid -> angle tables (8 lanes per row) ----
  {
    const int row = tid >> 3, oct = tid & 7;
    const float4* xr = (const float4*)(x + (size_t)(b0 + row) * 512) + oct * 16;
    float4 xs[16];
#pragma unroll
    for (int jj = 0; jj < 16; ++jj) xs[jj] = xr[jj];
    float acc[8];
#pragma unroll
    for (int q = 0; q < 8; ++q) {
      const float4* wr = (const float4*)(Wm + q * 512) + oct * 16;
      float a = 0.f;
#pragma unroll
      for (int jj = 0; jj < 16; ++jj) {
        float4 w = wr[jj];
        a += xs[jj].x*w.x + xs[jj].y*w.y + xs[jj].z*w.z + xs[jj].w*w.w;
      }
      acc[q] = a;
    }
#pragma unroll
    for (int off = 1; off <= 4; off <<= 1)
#pragma unroll
      for (int q = 0; q < 8; ++q)
        acc[q] += shfx(acc[q], off);
    if (oct == 0) {
#pragma unroll
      for (int q = 0; q < 8; ++q) {
        float t = (acc[q] + bvec[q]) * scale[q] + bias[q];
        float ang = PI_F / (1.f + __expf(-t));
        float h = 0.5f * ang;
        tTab[row][q]     = __cosf(h);
        tTab[row][8 + q] = __sinf(h);
      }
    }
  }
  __syncthreads();

  // ---- Phase B: psi tile -> Ash bf16. psi_i = prod_w t_w(bit_{7-w}(i)). ----
  {
    const int row = tid >> 3, oct = tid & 7;
    float T[8][2];
#pragma unroll
    for (int w = 0; w < 8; ++w) { T[w][0] = tTab[row][w]; T[w][1] = tTab[row][8+w]; }
    // i = oct*32 + m; i bits 7..5 = oct (wires 0..2), bits 4..0 = m (wires 3..7)
    float H = T[0][(oct >> 2) & 1] * T[1][(oct >> 1) & 1] * T[2][oct & 1];
    float a1[2], a2[4], a3[8], a4[16], a5[32];
    a1[0] = H * T[3][0]; a1[1] = H * T[3][1];
#pragma unroll
    for (int u = 0; u < 2; ++u) { a2[u*2] = a1[u]*T[4][0]; a2[u*2+1] = a1[u]*T[4][1]; }
#pragma unroll
    for (int u = 0; u < 4; ++u) { a3[u*2] = a2[u]*T[5][0]; a3[u*2+1] = a2[u]*T[5][1]; }
#pragma unroll
    for (int u = 0; u < 8; ++u) { a4[u*2] = a3[u]*T[6][0]; a4[u*2+1] = a3[u]*T[6][1]; }
#pragma unroll
    for (int u = 0; u < 16; ++u){ a5[u*2] = a4[u]*T[7][0]; a5[u*2+1] = a4[u]*T[7][1]; }
    unsigned short* arow = &Ash[row * APITCH + oct * 32];
#pragma unroll
    for (int g = 0; g < 4; ++g) {
      u16x8 v;
#pragma unroll
      for (int e = 0; e < 8; ++e) v[e] = f2bf(a5[g*8 + e]);
      *(u16x8*)(arow + g * 8) = v;
    }
  }
  __syncthreads();

  // ---- Phase C: GEMM. Wave wv owns n-strip [wv*128, wv*128+128). ----
  const int ln = lane & 15, quad = lane >> 4;
  f32x4 acc[2][8];
#pragma unroll
  for (int mt = 0; mt < 2; ++mt)
#pragma unroll
    for (int nt = 0; nt < 8; ++nt) acc[mt][nt] = (f32x4){0.f, 0.f, 0.f, 0.f};

#pragma unroll
  for (int ks = 0; ks < 8; ++ks) {
    const int k0 = ks * 32 + quad * 8;
    bf16x8 af[2], bf[8];
#pragma unroll
    for (int mt = 0; mt < 2; ++mt)
      af[mt] = *(const bf16x8*)(&Ash[(mt*16 + ln) * APITCH + k0]);
#pragma unroll
    for (int nt = 0; nt < 8; ++nt)
      bf[nt] = *(const bf16x8*)(Bt + (size_t)(wv*128 + nt*16 + ln) * 256 + k0);
#pragma unroll
    for (int mt = 0; mt < 2; ++mt)
#pragma unroll
      for (int nt = 0; nt < 8; ++nt)
        acc[mt][nt] = __builtin_amdgcn_mfma_f32_16x16x32_bf16(
            af[mt], bf[nt], acc[mt][nt], 0, 0, 0);
  }

  // ---- Epilogue: |phi|^2, signed trees -> partial <Z_w> per row ----
  // lane value at (m = mt*16 + quad*4 + r, n = wv*128 + nt*16 + ln).
  // i = n>>1: bits b7b6 = wv, b5..b3 = nt, b2..b0 = ln>>1.
#pragma unroll
  for (int mt = 0; mt < 2; ++mt)
#pragma unroll
    for (int r = 0; r < 4; ++r) {
      float p[8];
#pragma unroll
      for (int nt = 0; nt < 8; ++nt) {
        float v = acc[mt][nt][r];
        float v2 = v * v;
        p[nt] = v2 + shfx(v2, 1);          // re^2 + im^2 (lane pair n, n^1)
      }
      float u0[4], S4 = 0.f;
#pragma unroll
      for (int m2 = 0; m2 < 4; ++m2) {
        u0[m2] = p[2*m2] + p[2*m2+1];
        S4 += p[2*m2] - p[2*m2+1];         // nt bit0 = i b3 = wire 4
      }
      float u1[2], S3 = 0.f;
#pragma unroll
      for (int m2 = 0; m2 < 2; ++m2) {
        u1[m2] = u0[2*m2] + u0[2*m2+1];
        S3 += u0[2*m2] - u0[2*m2+1];       // nt bit1 = i b4 = wire 3
      }
      float S  = u1[0] + u1[1];
      float S2 = u1[0] - u1[1];            // nt bit2 = i b5 = wire 2
      float s5 = (lane & 8) ? -S : S;      // i b2 = wire 5
      float s6 = (lane & 4) ? -S : S;      // i b1 = wire 6
      float s7 = (lane & 2) ? -S : S;      // i b0 = wire 7
      float Tt = S;
      // Butterfly over ln bits 1..3 only: sums the 8 even (or odd) lanes of
      // each 16-lane group -> each |phi_i|^2 counted exactly once. No 0.5.
#pragma unroll
      for (int off = 2; off <= 8; off <<= 1) {
        Tt += shfx(Tt, off); s5 += shfx(s5, off); s6 += shfx(s6, off);
        s7 += shfx(s7, off); S2 += shfx(S2, off); S3 += shfx(S3, off);
        S4 += shfx(S4, off);
      }
      if (ln == 0) {
        const int m = mt*16 + quad*4 + r;
        float z0 = (wv & 2) ? -Tt : Tt;    // i b7 = wire 0
        float z1 = (wv & 1) ? -Tt : Tt;    // i b6 = wire 1
        *(float4*)&zpart[wv][m][0] = make_float4(z0, z1, S2, S3);
        *(float4*)&zpart[wv][m][4] = make_float4(S4, s5, s6, s7);
      }
    }
  __syncthreads();

  // ---- Cross-wave reduce + store ----
  if (tid < 64) {
    const int m = tid >> 1, h = tid & 1;
    float4 a = *(float4*)&zpart[0][m][h*4];
    float4 b = *(float4*)&zpart[1][m][h*4];
    float4 c = *(float4*)&zpart[2][m][h*4];
    float4 d = *(float4*)&zpart[3][m][h*4];
    float4 rsl = make_float4(a.x+b.x+c.x+d.x, a.y+b.y+c.y+d.y,
                             a.z+b.z+c.z+d.z, a.w+b.w+c.w+d.w);
    *(float4*)(out + (size_t)(b0 + m) * 8 + h * 4) = rsl;
  }
}

}  // namespace

extern "C" void kernel_launch(void* const* d_in, const int* in_sizes, int n_in,
                              void* d_out, int out_size, void* d_ws, size_t ws_size,
                              hipStream_t stream) {
  const float* x     = (const float*)d_in[0];  // (8192, 512)
  const float* Wm    = (const float*)d_in[1];  // (8, 512)
  const float* bvec  = (const float*)d_in[2];  // (8,)
  const float* scale = (const float*)d_in[3];  // (8,)
  const float* bias  = (const float*)d_in[4];  // (8,)
  const float* qw    = (const float*)d_in[5];  // (3, 8, 3)
  float* out = (float*)d_out;                  // (8192, 8)
  (void)in_sizes; (void)n_in; (void)out_size; (void)ws_size;

  unsigned short* Bt = (unsigned short*)d_ws;  // 512 x 256 bf16 = 256 KB

  hipLaunchKernelGGL(build_u_kernel, dim3(64), dim3(256), 0, stream, qw, Bt);
  hipLaunchKernelGGL(qgemm_kernel, dim3(256), dim3(256), 0, stream,
                     x, Wm, bvec, scale, bias, Bt, out);
}